// Round 4
// baseline (344.330 us; speedup 1.0000x reference)
//
#include <hip/hip_runtime.h>
#include <math.h>
#include <stdint.h>

#define VOCAB 50257
#define KD 5
#define NBATCH 256
#define NSPLIT 8
#define NT1 256
#define NT2 1024
#define NW2 (NT2 / 64)
#define TILE 1024
#define NTILES ((VOCAB + TILE - 1) / TILE) /* 50 */

// ---------------- K1: row-0 per-tile exp sums + per-segment max ------------
// grid = NBATCH*NSPLIT blocks. Block (b,seg) handles tiles t = seg, seg+8,...
// tsum[b][t] = sum of (double)expf(x) over tile t (un-normalized, fixed-order
// block reduction -> deterministic). mpart[b][seg] = max of (double)expf(x).
__global__ __launch_bounds__(NT1) void row0_stats_kernel(
    const float* __restrict__ logits,
    double* __restrict__ tsum,   // [B, NTILES]
    double* __restrict__ mpart)  // [B, NSPLIT]
{
    const int bid = blockIdx.x;
    const int b   = bid / NSPLIT;
    const int seg = bid % NSPLIT;
    const int tid = threadIdx.x;
    const int lane = tid & 63, wv = tid >> 6;
    __shared__ double sw[NT1 / 64];

    const float* row = logits + (size_t)b * KD * (size_t)VOCAB; // row 0
    double mLoc = 0.0;
    for (int t = seg; t < NTILES; t += NSPLIT) {
        int base = t * TILE;
        double s = 0.0;
        #pragma unroll
        for (int j = 0; j < TILE / NT1; ++j) {
            int idx = base + j * NT1 + tid;
            if (idx < VOCAB) {
                double e = (double)expf(row[idx]);
                s += e;
                mLoc = fmax(mLoc, e);
            }
        }
        for (int off = 32; off; off >>= 1) s += __shfl_down(s, off, 64);
        if (lane == 0) sw[wv] = s;
        __syncthreads();
        if (tid == 0) {
            double S = 0.0;
            for (int w = 0; w < NT1 / 64; ++w) S += sw[w];
            tsum[b * NTILES + t] = S;
        }
        __syncthreads();
    }
    for (int off = 32; off; off >>= 1) mLoc = fmax(mLoc, __shfl_down(mLoc, off, 64));
    if (lane == 0) sw[wv] = mLoc;
    __syncthreads();
    if (tid == 0) {
        double M = sw[0];
        for (int w = 1; w < NT1 / 64; ++w) M = fmax(M, sw[w]);
        mpart[b * NSPLIT + seg] = M;
    }
}

// ---------------- K2: accept scan + fallback sampling ----------------------
__global__ __launch_bounds__(NT2) void decide_sample_kernel(
    const int* __restrict__ dtok,     // [B,K]
    const float* __restrict__ dlp,    // [B,K]
    const float* __restrict__ logits, // [B,K,V]
    const float* __restrict__ rnd,    // [B,K]
    const float* __restrict__ usmp,   // [B]
    const double* __restrict__ tsum,  // [B,NTILES]
    const double* __restrict__ mpart, // [B,NSPLIT]
    int* __restrict__ out)            // [B*K + B + B]
{
    const int b    = blockIdx.x;
    const int tid  = threadIdx.x;
    const int lane = tid & 63;
    const int wv   = tid >> 6;

    __shared__ double s_w[NW2];
    __shared__ double s_tileA[NTILES];
    __shared__ double s_tileR[NTILES];
    __shared__ double s_dbc[2];
    __shared__ int    s_ibc[2];
    __shared__ int    s_found;

    const float* row0 = logits + (size_t)b * KD * (size_t)VOCAB;

    // ---- r = 0 decision from precomputed stats ----
    if (tid < NTILES) s_tileR[tid] = tsum[b * NTILES + tid];
    if (wv == 1) {
        double m = (lane < NSPLIT) ? mpart[b * NSPLIT + lane] : 0.0;
        for (int off = 4; off; off >>= 1) m = fmax(m, __shfl_down(m, off, 64));
        if (lane == 0) s_dbc[1] = m;
    }
    __syncthreads();
    if (tid == 0) {
        double Z = 0.0;
        for (int t = 0; t < NTILES; ++t) Z += s_tileR[t]; // fixed order
        s_dbc[0] = Z;
        int    tok = dtok[b * KD];
        double tlp = (double)row0[tok] - log(Z);
        double ap  = exp(tlp - (double)dlp[b * KD]);
        if (ap > 1.0) ap = 1.0;
        s_ibc[0] = ((double)rnd[b * KD] < ap) ? 1 : 0;
        s_found  = 0x7FFFFFFF;
    }
    __syncthreads();
    double Zsel = s_dbc[0];
    double mx0  = s_dbc[1];
    int    n_acc = KD;
    if (!s_ibc[0]) {
        n_acc = 0;
    } else {
        // rare (~0.7%): continue lazy scan rows 1..K-1 with full row sums
        for (int r = 1; r < KD; ++r) {
            const float* rrow = logits + ((size_t)b * KD + r) * (size_t)VOCAB;
            int head = (int)((4u - ((((uintptr_t)rrow) >> 2) & 3u)) & 3u);
            double local = 0.0;
            if (tid < head) local += (double)expf(rrow[tid]);
            int nvec = (VOCAB - head) >> 2;
            const float4* row4 = (const float4*)(rrow + head);
            for (int i = tid; i < nvec; i += NT2) {
                float4 x = row4[i];
                local += (double)expf(x.x) + (double)expf(x.y)
                       + (double)expf(x.z) + (double)expf(x.w);
            }
            int ts = head + (nvec << 2);
            int tc = VOCAB - ts;
            if (tid < tc) local += (double)expf(rrow[ts + tid]);
            for (int off = 32; off; off >>= 1) local += __shfl_down(local, off, 64);
            if (lane == 0) s_w[wv] = local;
            __syncthreads();
            if (tid == 0) {
                double Z = 0.0;
                for (int w = 0; w < NW2; ++w) Z += s_w[w];
                s_dbc[0] = Z;
                int    tok = dtok[b * KD + r];
                double tlp = (double)rrow[tok] - log(Z);
                double ap  = exp(tlp - (double)dlp[b * KD + r]);
                if (ap > 1.0) ap = 1.0;
                s_ibc[0] = ((double)rnd[b * KD + r] < ap) ? 1 : 0;
            }
            __syncthreads();
            Zsel = s_dbc[0];
            int acc = s_ibc[0];
            __syncthreads();
            if (!acc) { n_acc = r; break; }
        }
    }

    // ---- write accepted tokens / n ----
    if (tid == 0) {
        for (int r = 0; r < KD; ++r)
            out[b * KD + r] = (r < n_acc) ? dtok[b * KD + r] : 0;
        out[NBATCH * KD + b] = n_acc;
        if (n_acc >= KD) out[NBATCH * KD + NBATCH + b] = 0;
    }
    if (n_acc >= KD) return; // block-uniform

    const int    rp   = n_acc;
    const float* row  = logits + ((size_t)b * KD + rp) * (size_t)VOCAB;
    const double invZ = 1.0 / Zsel;
    const double dp   = exp((double)dlp[b * KD + rp]);

    // mode: 0 = raw un-normalized (fast r0 path), 1 = adjusted, 2 = raw norm.
    if (rp == 0 && !(mx0 * invZ > dp)) {
        // ---- fast raw path: tiles already in s_tileR, Tot == Zsel ----
        __syncthreads(); // ensure all threads consumed Zsel before overwrite
        if (tid == 0) {
            double T = (double)usmp[b] * Zsel;
            double P = 0.0;
            int    ct = NTILES - 1;
            for (int t = 0; t < NTILES; ++t) {
                if (P + s_tileR[t] >= T || t == NTILES - 1) { ct = t; break; }
                P += s_tileR[t];
            }
            s_dbc[0] = P; s_dbc[1] = T; s_ibc[0] = ct; s_ibc[1] = 0;
        }
        __syncthreads();
    } else if (rp == 0) {
        // ---- adjusted-only full pass (S > 0 guaranteed by max test) ----
        for (int t = wv; t < NTILES; t += NW2) {
            double aS = 0.0;
            int base = t * TILE;
            for (int j = 0; j < TILE / 64; ++j) {
                int idx = base + j * 64 + lane;
                if (idx < VOCAB) {
                    double p = (double)expf(row[idx]) * invZ;
                    double a = p - dp;
                    if (a > 0.0) aS += a;
                }
            }
            for (int off = 32; off; off >>= 1) aS += __shfl_down(aS, off, 64);
            if (lane == 0) s_tileA[t] = aS;
        }
        __syncthreads();
        if (tid == 0) {
            double S = 0.0;
            for (int t = 0; t < NTILES; ++t) S += s_tileA[t];
            double T = (double)usmp[b] * S;
            double P = 0.0;
            int    ct = NTILES - 1;
            for (int t = 0; t < NTILES; ++t) {
                if (P + s_tileA[t] >= T || t == NTILES - 1) { ct = t; break; }
                P += s_tileA[t];
            }
            s_dbc[0] = P; s_dbc[1] = T; s_ibc[0] = ct; s_ibc[1] = 1;
        }
        __syncthreads();
    } else {
        // ---- rare rp>=1: full pass, both sums (round-3 logic) ----
        for (int t = wv; t < NTILES; t += NW2) {
            double aS = 0.0, rS = 0.0;
            int base = t * TILE;
            for (int j = 0; j < TILE / 64; ++j) {
                int idx = base + j * 64 + lane;
                if (idx < VOCAB) {
                    double p = (double)expf(row[idx]) * invZ;
                    rS += p;
                    double a = p - dp;
                    if (a > 0.0) aS += a;
                }
            }
            for (int off = 32; off; off >>= 1) {
                aS += __shfl_down(aS, off, 64);
                rS += __shfl_down(rS, off, 64);
            }
            if (lane == 0) { s_tileA[t] = aS; s_tileR[t] = rS; }
        }
        __syncthreads();
        if (tid == 0) {
            double S = 0.0;
            for (int t = 0; t < NTILES; ++t) S += s_tileA[t];
            int useAdj = (S > 0.0) ? 1 : 0;
            double Tot = S;
            if (!useAdj) {
                Tot = 0.0;
                for (int t = 0; t < NTILES; ++t) Tot += s_tileR[t];
            }
            double T = (double)usmp[b] * Tot;
            const double* tiles = useAdj ? s_tileA : s_tileR;
            double P = 0.0;
            int    ct = NTILES - 1;
            for (int t = 0; t < NTILES; ++t) {
                if (P + tiles[t] >= T || t == NTILES - 1) { ct = t; break; }
                P += tiles[t];
            }
            s_dbc[0] = P; s_dbc[1] = T; s_ibc[0] = ct; s_ibc[1] = useAdj ? 1 : 2;
        }
        __syncthreads();
    }

    // ---- in-tile ordered scan -> sampled index ----
    {
        double Pb   = s_dbc[0];
        double T    = s_dbc[1];
        int    ct   = s_ibc[0];
        int    mode = s_ibc[1];
        int    idx  = ct * TILE + tid;
        double g    = 0.0;
        if (idx < VOCAB) {
            double e = (double)expf(row[idx]);
            if (mode == 0) {
                g = e;
            } else {
                double p = e * invZ;
                if (mode == 1) { double a = p - dp; g = (a > 0.0) ? a : 0.0; }
                else           { g = p; }
            }
        }
        double sc = g;
        for (int off = 1; off < 64; off <<= 1) {
            double v = __shfl_up(sc, (unsigned)off, 64);
            if (lane >= off) sc += v;
        }
        if (lane == 63) s_w[wv] = sc;
        __syncthreads();
        double woff = 0.0;
        for (int w = 0; w < wv; ++w) woff += s_w[w];
        double incl = Pb + woff + sc;
        if (idx < VOCAB && incl >= T) atomicMin(&s_found, idx);
        __syncthreads();
        if (tid == 0) {
            int smp = s_found;
            if (smp == 0x7FFFFFFF) { // rounding guard
                smp = ct * TILE + TILE - 1;
                if (smp > VOCAB - 1) smp = VOCAB - 1;
            }
            out[NBATCH * KD + NBATCH + b] = smp;
        }
    }
}

extern "C" void kernel_launch(void* const* d_in, const int* in_sizes, int n_in,
                              void* d_out, int out_size, void* d_ws, size_t ws_size,
                              hipStream_t stream) {
    const int*   dtok   = (const int*)d_in[0];
    const float* dlp    = (const float*)d_in[1];
    const float* logits = (const float*)d_in[2];
    const float* rnd    = (const float*)d_in[3];
    const float* usmp   = (const float*)d_in[4];
    int*         out    = (int*)d_out;
    double*      tsum   = (double*)d_ws;                       // 100 KB
    double*      mpart  = (double*)d_ws + NBATCH * NTILES;     // +16 KB
    (void)in_sizes; (void)n_in; (void)out_size; (void)ws_size;

    row0_stats_kernel<<<dim3(NBATCH * NSPLIT), dim3(NT1), 0, stream>>>(
        logits, tsum, mpart);
    decide_sample_kernel<<<dim3(NBATCH), dim3(NT2), 0, stream>>>(
        dtok, dlp, logits, rnd, usmp, tsum, mpart, out);
}